// Round 9
// baseline (1102.211 us; speedup 1.0000x reference)
//
#include <hip/hip_runtime.h>

// ================= global barrier (persistent kernel) =====================
// All blocks co-resident (256 blocks x 1024 thr = 16 waves/CU, low VGPR/LDS).
// Device-scope atomics + all-thread fences (XCD L2 non-coherence safe).
// cnt/gen self-init from 0xAA poison via CAS; gen is monotonic so leftover
// state from a previous (un-poisoned) call is also fine.

__device__ __forceinline__ void gbar(int* cnt, int* gen, int nb){
  __threadfence();
  __syncthreads();
  if (threadIdx.x == 0){
    int my = __hip_atomic_load(gen, __ATOMIC_RELAXED, __HIP_MEMORY_SCOPE_AGENT);
    int a  = __hip_atomic_fetch_add(cnt, 1, __ATOMIC_ACQ_REL, __HIP_MEMORY_SCOPE_AGENT);
    if (a == nb - 1){
      __hip_atomic_store(cnt, 0, __ATOMIC_RELAXED, __HIP_MEMORY_SCOPE_AGENT);
      __hip_atomic_fetch_add(gen, 1, __ATOMIC_ACQ_REL, __HIP_MEMORY_SCOPE_AGENT);
    } else {
      while (__hip_atomic_load(gen, __ATOMIC_RELAXED, __HIP_MEMORY_SCOPE_AGENT) == my)
        __builtin_amdgcn_s_sleep(2);
    }
  }
  __syncthreads();
  __threadfence();
}

// ============ fused CSR build + weight packing (ONE kernel) ===============
// Phases: 0 zero deg + pack wc/bc | 1 hist | 2 block scan | 3 scan blocksums
//         4 finalize rowptr/self-loop/cursor | 5 scatter.  Requires n <= 256*1024.

#define CSRNB 256
#define CSRNT 1024

__global__ __launch_bounds__(CSRNT, 4) void k_csr_build(
    const int* __restrict__ srcp, const int* __restrict__ dstp, int E, int n,
    const float* __restrict__ w1_l, const float* __restrict__ w1_r,
    const float* __restrict__ b1_l, const float* __restrict__ b1_r,
    const float* __restrict__ w2_l, const float* __restrict__ w2_r,
    const float* __restrict__ b2_l, const float* __restrict__ b2_r,
    float* __restrict__ wc1, float* __restrict__ bc1,
    float* __restrict__ wc2, float* __restrict__ bc2,
    int* __restrict__ deg, int* __restrict__ rowptr, int* __restrict__ cursor,
    int* __restrict__ srcs, int* __restrict__ bsum, int* bar){
  __shared__ int s[CSRNT];
  int tid = threadIdx.x, bid = blockIdx.x;
  int g = bid*CSRNT + tid;
  const int GT = CSRNB*CSRNT;
  if (tid == 0){
    atomicCAS(&bar[0], (int)0xAAAAAAAAu, 0);
    atomicCAS(&bar[1], (int)0xAAAAAAAAu, 0);
  }
  // phase 0: zero deg + pack weights/biases
  for (int i = g; i < n; i += GT) deg[i] = 0;
  for (int i = g; i < 128*256; i += GT){
    int k = i >> 8, j = i & 255;
    wc1[i] = (j < 128) ? w1_l[k*128 + j] : w1_r[k*128 + (j - 128)];
  }
  for (int i = g; i < 128*128; i += GT){
    int k = i >> 7, j = i & 127;
    wc2[i] = (j < 64) ? w2_l[k*64 + j] : w2_r[k*64 + (j - 64)];
  }
  if (g < 256) bc1[g] = (g < 128) ? b1_l[g] : b1_r[g - 128];
  if (g < 128) bc2[g] = (g < 64)  ? b2_l[g] : b2_r[g - 64];
  gbar(&bar[0], &bar[1], CSRNB);
  // phase 1: histogram of destinations
  for (int e = g; e < E; e += GT) atomicAdd(&deg[dstp[e]], 1);
  gbar(&bar[0], &bar[1], CSRNB);
  // phase 2: per-block inclusive scan of deg+1 (one element per thread)
  int v = (g < n) ? deg[g] + 1 : 0;   // +1 = self loop
  s[tid] = v;
  __syncthreads();
  for (int off = 1; off < CSRNT; off <<= 1){
    int t = (tid >= off) ? s[tid - off] : 0;
    __syncthreads();
    s[tid] += t;
    __syncthreads();
  }
  int excl = s[tid] - v;
  if (tid == CSRNT-1) bsum[bid] = s[tid];
  gbar(&bar[0], &bar[1], CSRNB);
  // phase 3: block 0 turns block sums into exclusive prefixes
  if (bid == 0){
    int bv = (tid < CSRNB) ? bsum[tid] : 0;
    s[tid] = bv;
    __syncthreads();
    for (int off = 1; off < CSRNT; off <<= 1){
      int t = (tid >= off) ? s[tid - off] : 0;
      __syncthreads();
      s[tid] += t;
      __syncthreads();
    }
    if (tid < CSRNB) bsum[tid] = s[tid] - bv;
  }
  gbar(&bar[0], &bar[1], CSRNB);
  // phase 4: finalize rowptr, seed self-loop + cursor
  if (g < n){
    int b = excl + bsum[bid];
    rowptr[g] = b;
    srcs[b] = g;
    cursor[g] = b + 1;
  }
  if (g == 0) rowptr[n] = E + n;
  gbar(&bar[0], &bar[1], CSRNB);
  // phase 5: scatter edges into CSR
  for (int e = g; e < E; e += GT){
    int p = atomicAdd(&cursor[dstp[e]], 1);
    srcs[p] = srcp[e];
  }
}

// ---------------- fp32 GEMM 128x128 tile, 8x8 micro (main GEMMs) -----------
// Split-half LDS layout -> 2-way bank alias (free). K%16==0, N%128==0; M guarded.

#define GBM 128
#define GBN 128
#define GBK 16

__device__ __forceinline__ int half_perm(int j){
  return ((j >> 3) << 2) + (j & 3) + ((j & 4) ? 64 : 0);
}

__global__ __launch_bounds__(256, 2) void k_gemm128(
    const float* __restrict__ A, const float* __restrict__ W,
    const float* __restrict__ bias, float* __restrict__ C,
    int M, int K, int N){
  __shared__ float As[GBK][GBM];
  __shared__ float Ws[GBK][GBN];
  int bm = blockIdx.x * GBM, bn = blockIdx.y * GBN;
  int tid = threadIdx.x;
  int tx = tid & 15, ty = tid >> 4;
  float acc[8][8] = {};
  for (int k0 = 0; k0 < K; k0 += GBK){
    #pragma unroll
    for (int l = 0; l < 2; l++){
      int idx = tid + l*256;              // 0..511
      int r = idx >> 2, kq = (idx & 3) * 4;
      float4 v = make_float4(0.f, 0.f, 0.f, 0.f);
      if (bm + r < M) v = *(const float4*)(A + (size_t)(bm + r)*K + k0 + kq);
      int rp = half_perm(r);
      As[kq+0][rp] = v.x; As[kq+1][rp] = v.y; As[kq+2][rp] = v.z; As[kq+3][rp] = v.w;
      int kr = idx >> 5, wc = (idx & 31) * 4;
      int wp = ((wc >> 3) << 2) + ((wc & 4) ? 64 : 0);
      *(float4*)(&Ws[kr][wp]) = *(const float4*)(W + (size_t)(k0 + kr)*N + bn + wc);
    }
    __syncthreads();
    #pragma unroll
    for (int k = 0; k < GBK; k++){
      float a[8], w[8];
      *(float4*)(a)   = *(const float4*)(&As[k][ty*4]);
      *(float4*)(a+4) = *(const float4*)(&As[k][64 + ty*4]);
      *(float4*)(w)   = *(const float4*)(&Ws[k][tx*4]);
      *(float4*)(w+4) = *(const float4*)(&Ws[k][64 + tx*4]);
      #pragma unroll
      for (int i = 0; i < 8; i++)
        #pragma unroll
        for (int j = 0; j < 8; j++)
          acc[i][j] = fmaf(a[i], w[j], acc[i][j]);
    }
    __syncthreads();
  }
  #pragma unroll
  for (int i = 0; i < 8; i++){
    int r = bm + ty*8 + i;
    if (r < M){
      #pragma unroll
      for (int j4 = 0; j4 < 2; j4++){
        float4 o;
        int cb = bn + tx*8 + j4*4;
        o.x = acc[i][j4*4+0] + bias[cb + 0];
        o.y = acc[i][j4*4+1] + bias[cb + 1];
        o.z = acc[i][j4*4+2] + bias[cb + 2];
        o.w = acc[i][j4*4+3] + bias[cb + 3];
        *(float4*)(C + (size_t)r*N + cb) = o;
      }
    }
  }
}

// ---------------- DPP adds (VALU pipe, no DS ops) ----------------

template<int CTRL>
__device__ __forceinline__ float dpp_add(float x){
  int t = __builtin_amdgcn_update_dpp(0, __float_as_int(x), CTRL, 0xf, 0xf, true);
  return x + __int_as_float(t);
}

__device__ __forceinline__ float wave_sum_bcast(float x){
  x = dpp_add<0x111>(x);   // row_shr:1
  x = dpp_add<0x112>(x);   // row_shr:2
  x = dpp_add<0x114>(x);   // row_shr:4
  x = dpp_add<0x118>(x);   // row_shr:8
  x = dpp_add<0x142>(x);   // row_bcast:15
  x = dpp_add<0x143>(x);   // row_bcast:31
  return __int_as_float(__builtin_amdgcn_readlane(__float_as_int(x), 63));
}

// ---------------- fused GATv2 layer (8-deep gather pipeline) --------------
// One wave per (node, head); lane = feature. xr/att loaded once per node.
// xlr layout: [n][H*128]: xl head-major at [h*64..), xr at [H*64 + h*64..).

template<int H>
__global__ __launch_bounds__(256) void k_gat_fused(
    const float* __restrict__ xlr, const int* __restrict__ rowptr,
    const int* __restrict__ srcs, const float* __restrict__ att,
    const float* __restrict__ bias, float* __restrict__ out, int n){
  int gid = blockIdx.x * blockDim.x + threadIdx.x;
  int wave = gid >> 6, lane = gid & 63;
  int nd = wave / H, h = wave % H;
  if (nd >= n) return;
  const int stride = H * 128;
  const float* __restrict__ xh = xlr + h*64 + lane;
  float xr = xlr[(size_t)nd*stride + H*64 + h*64 + lane];
  float av = att[h*64 + lane];
  float acc = 0.f, den = 0.f;
  int s0 = rowptr[nd], s1 = rowptr[nd+1];
  for (int base = s0; base < s1; base += 64){
    int idx = base + lane;
    int sv = (idx < s1) ? srcs[idx] : 0;
    int cnt = min(64, s1 - base);
    int i = 0;
    for (; i + 8 <= cnt; i += 8){
      int a0 = __builtin_amdgcn_readlane(sv, i+0);
      int a1 = __builtin_amdgcn_readlane(sv, i+1);
      int a2 = __builtin_amdgcn_readlane(sv, i+2);
      int a3 = __builtin_amdgcn_readlane(sv, i+3);
      int a4 = __builtin_amdgcn_readlane(sv, i+4);
      int a5 = __builtin_amdgcn_readlane(sv, i+5);
      int a6 = __builtin_amdgcn_readlane(sv, i+6);
      int a7 = __builtin_amdgcn_readlane(sv, i+7);
      float x0 = xh[(size_t)a0*stride], x1 = xh[(size_t)a1*stride];
      float x2 = xh[(size_t)a2*stride], x3 = xh[(size_t)a3*stride];
      float x4 = xh[(size_t)a4*stride], x5 = xh[(size_t)a5*stride];
      float x6 = xh[(size_t)a6*stride], x7 = xh[(size_t)a7*stride];
      float t0 = x0 + xr, t1 = x1 + xr, t2 = x2 + xr, t3 = x3 + xr;
      float t4 = x4 + xr, t5 = x5 + xr, t6 = x6 + xr, t7 = x7 + xr;
      float e0 = __expf(wave_sum_bcast(fmaxf(t0, 0.2f*t0)*av));
      float e1 = __expf(wave_sum_bcast(fmaxf(t1, 0.2f*t1)*av));
      float e2 = __expf(wave_sum_bcast(fmaxf(t2, 0.2f*t2)*av));
      float e3 = __expf(wave_sum_bcast(fmaxf(t3, 0.2f*t3)*av));
      float e4 = __expf(wave_sum_bcast(fmaxf(t4, 0.2f*t4)*av));
      float e5 = __expf(wave_sum_bcast(fmaxf(t5, 0.2f*t5)*av));
      float e6 = __expf(wave_sum_bcast(fmaxf(t6, 0.2f*t6)*av));
      float e7 = __expf(wave_sum_bcast(fmaxf(t7, 0.2f*t7)*av));
      den += ((e0+e1)+(e2+e3)) + ((e4+e5)+(e6+e7));
      acc = fmaf(e0,x0,acc); acc = fmaf(e1,x1,acc);
      acc = fmaf(e2,x2,acc); acc = fmaf(e3,x3,acc);
      acc = fmaf(e4,x4,acc); acc = fmaf(e5,x5,acc);
      acc = fmaf(e6,x6,acc); acc = fmaf(e7,x7,acc);
    }
    for (; i < cnt; i++){
      int a = __builtin_amdgcn_readlane(sv, i);
      float x = xh[(size_t)a*stride];
      float t = x + xr;
      float e = __expf(wave_sum_bcast(fmaxf(t, 0.2f*t)*av));
      den += e;
      acc = fmaf(e, x, acc);
    }
  }
  out[(size_t)nd*(H*64) + h*64 + lane] =
      fmaxf(acc / (den + 1e-16f) + bias[h*64 + lane], 0.f);
}

// ---------------- gate: relu(h2@gw1+gb1)@gw2+gb2 -> exp, fused ------------
// 64x64 GEMM tile; epilogue folds the gw2 dot via 4-step DPP reduce over
// each 16-lane tx group (DPP row == tx group), lane tx==15 writes exn.

__global__ __launch_bounds__(256) void k_gate(
    const float* __restrict__ h2, const float* __restrict__ gw1,
    const float* __restrict__ gb1, const float* __restrict__ gw2,
    const float* __restrict__ gb2, float* __restrict__ exn, int M){
  __shared__ float As[32][64 + 4];
  __shared__ float Ws[32][64];
  int bm = blockIdx.x * 64;
  int tid = threadIdx.x;
  int tx = tid & 15, ty = tid >> 4;
  float acc[4][4] = {};
  for (int k0 = 0; k0 < 64; k0 += 32){
    #pragma unroll
    for (int l = 0; l < 2; l++){
      int idx = tid + l*256;
      int r = idx >> 3, c4 = (idx & 7) * 4;
      float4 v = make_float4(0.f, 0.f, 0.f, 0.f);
      if (bm + r < M) v = *(const float4*)(h2 + (size_t)(bm + r)*64 + k0 + c4);
      As[c4+0][r] = v.x; As[c4+1][r] = v.y; As[c4+2][r] = v.z; As[c4+3][r] = v.w;
      int kr = idx >> 4, wc4 = (idx & 15) * 4;
      *(float4*)(&Ws[kr][wc4]) = *(const float4*)(gw1 + (size_t)(k0 + kr)*64 + wc4);
    }
    __syncthreads();
    #pragma unroll
    for (int k = 0; k < 32; k++){
      float4 a4 = *(const float4*)(&As[k][ty*4]);
      float4 w4 = *(const float4*)(&Ws[k][tx*4]);
      float av[4] = {a4.x, a4.y, a4.z, a4.w};
      float wv[4] = {w4.x, w4.y, w4.z, w4.w};
      #pragma unroll
      for (int i = 0; i < 4; i++)
        #pragma unroll
        for (int j = 0; j < 4; j++)
          acc[i][j] = fmaf(av[i], wv[j], acc[i][j]);
    }
    __syncthreads();
  }
  float4 b4 = *(const float4*)(gb1 + tx*4);
  float4 w2 = *(const float4*)(gw2 + tx*4);
  float gb2v = gb2[0];
  #pragma unroll
  for (int i = 0; i < 4; i++){
    float p = fmaxf(acc[i][0] + b4.x, 0.f) * w2.x;
    p = fmaf(fmaxf(acc[i][1] + b4.y, 0.f), w2.y, p);
    p = fmaf(fmaxf(acc[i][2] + b4.z, 0.f), w2.z, p);
    p = fmaf(fmaxf(acc[i][3] + b4.w, 0.f), w2.w, p);
    p = dpp_add<0x111>(p);
    p = dpp_add<0x112>(p);
    p = dpp_add<0x114>(p);
    p = dpp_add<0x118>(p);     // lane tx==15 holds the 16-lane row sum
    if (tx == 15){
      int r = bm + ty*4 + i;
      if (r < M) exn[r] = __expf(p + gb2v);
    }
  }
}

// ---------------- pool + MLP head: one block per batch segment ----------------

__global__ __launch_bounds__(1024) void k_pool_mlp(
    const float* __restrict__ h2, const float* __restrict__ exn,
    const int* __restrict__ batch, int n,
    const float* __restrict__ l1w, const float* __restrict__ l1b,
    const float* __restrict__ l2w, const float* __restrict__ l2b,
    float* __restrict__ out){
  __shared__ float accs[16][64];
  __shared__ float dens[16];
  int b = blockIdx.x;
  int tid = threadIdx.x, lane = tid & 63, wv = tid >> 6;
  int lo = 0, hi = n;
  while (lo < hi){ int m = (lo + hi) >> 1; if (batch[m] < b) lo = m + 1; else hi = m; }
  int start = lo;
  hi = n;
  while (lo < hi){ int m = (lo + hi) >> 1; if (batch[m] < b + 1) lo = m + 1; else hi = m; }
  int end = lo;
  float acc = 0.f, den = 0.f;
  for (int nd = start + wv; nd < end; nd += 16){
    float ex = exn[nd];
    den += ex;
    acc = fmaf(ex, h2[(size_t)nd*64 + lane], acc);
  }
  accs[wv][lane] = acc;
  if (lane == 0) dens[wv] = den;
  __syncthreads();
  if (wv == 0){
    float p = 0.f, d = 0.f;
    #pragma unroll
    for (int w = 0; w < 16; w++){ p += accs[w][lane]; d += dens[w]; }
    p = p / (d + 1e-16f);
    float t = l1b[lane];
    #pragma unroll
    for (int k = 0; k < 64; k++)
      t = fmaf(__shfl(p, k, 64), l1w[k*64 + lane], t);
    t = fmaxf(t, 0.f) * l2w[lane];
    #pragma unroll
    for (int off = 32; off; off >>= 1) t += __shfl_xor(t, off, 64);
    if (lane == 0) out[b] = t + l2b[0];
  }
}

// ---------------- launch (7 dispatches) ----------------

extern "C" void kernel_launch(void* const* d_in, const int* in_sizes, int n_in,
                              void* d_out, int out_size, void* d_ws, size_t ws_size,
                              hipStream_t stream){
  const float* x    = (const float*)d_in[0];
  const int*   ei   = (const int*)  d_in[1];
  const int*   batch= (const int*)  d_in[2];
  const float* w1_l = (const float*)d_in[3];  const float* b1_l = (const float*)d_in[4];
  const float* w1_r = (const float*)d_in[5];  const float* b1_r = (const float*)d_in[6];
  const float* att1 = (const float*)d_in[7];  const float* bias1= (const float*)d_in[8];
  const float* w2_l = (const float*)d_in[9];  const float* b2_l = (const float*)d_in[10];
  const float* w2_r = (const float*)d_in[11]; const float* b2_r = (const float*)d_in[12];
  const float* att2 = (const float*)d_in[13]; const float* bias2= (const float*)d_in[14];
  const float* gw1  = (const float*)d_in[15]; const float* gb1  = (const float*)d_in[16];
  const float* gw2  = (const float*)d_in[17]; const float* gb2  = (const float*)d_in[18];
  const float* l1w  = (const float*)d_in[19]; const float* l1b  = (const float*)d_in[20];
  const float* l2w  = (const float*)d_in[21]; const float* l2b  = (const float*)d_in[22];

  const int n = in_sizes[0] / 128;
  const int E = in_sizes[1] / 2;
  const int Bb = out_size;
  const int Etot = E + n;
  const int* srcp = ei;
  const int* dstp = ei + E;

  char* wsbase = (char*)d_ws;
  size_t off = 0;
  auto alloc = [&](size_t bytes)->char*{
    char* p = wsbase + off;
    off = (off + bytes + 255) & ~(size_t)255;
    return p;
  };
  int*   deg    = (int*)  alloc((size_t)n*4);
  int*   rowptr = (int*)  alloc((size_t)(n+1)*4);
  int*   cursor = (int*)  alloc((size_t)n*4);
  int*   bsum   = (int*)  alloc(CSRNB*4);
  int*   bar    = (int*)  alloc(256);
  int*   srcs   = (int*)  alloc((size_t)Etot*4);
  float* wc1    = (float*)alloc(128*256*4);
  float* bc1    = (float*)alloc(256*4);
  float* wc2    = (float*)alloc(128*128*4);
  float* bc2    = (float*)alloc(128*4);
  float* big    = (float*)alloc((size_t)n*256*4);  // xlr1; later xlr2 + h2
  float* h1     = (float*)alloc((size_t)n*128*4);  // h1; later exn
  float* xlr1 = big;
  float* xlr2 = big;
  float* h2   = big + (size_t)n*128;
  float* exn  = h1;                     // reuse after layer-2 gemm consumed h1

  // 1) CSR + packing (persistent, global-barrier phased)
  k_csr_build<<<CSRNB, CSRNT, 0, stream>>>(
      srcp, dstp, E, n,
      w1_l, w1_r, b1_l, b1_r, w2_l, w2_r, b2_l, b2_r,
      wc1, bc1, wc2, bc2,
      deg, rowptr, cursor, srcs, bsum, bar);

  // 2) layer-1 projection
  dim3 g1((n + GBM - 1)/GBM, 256/GBN);
  k_gemm128<<<g1, 256, 0, stream>>>(x, wc1, bc1, xlr1, n, 128, 256);

  // 3) layer-1 fused GAT
  long long thr1 = (long long)n * 2 * 64;
  k_gat_fused<2><<<(int)((thr1 + 255)/256), 256, 0, stream>>>(xlr1, rowptr, srcs, att1, bias1, h1, n);

  // 4) layer-2 projection
  dim3 g2((n + GBM - 1)/GBM, 128/GBN);
  k_gemm128<<<g2, 256, 0, stream>>>(h1, wc2, bc2, xlr2, n, 128, 128);

  // 5) layer-2 fused GAT
  long long thr2 = (long long)n * 64;
  k_gat_fused<1><<<(int)((thr2 + 255)/256), 256, 0, stream>>>(xlr2, rowptr, srcs, att2, bias2, h2, n);

  // 6) gate (gemm + gw2-dot + exp fused)
  k_gate<<<(n + 63)/64, 256, 0, stream>>>(h2, gw1, gb1, gw2, gb2, exn, n);

  // 7) pool + MLP head
  k_pool_mlp<<<Bb, 1024, 0, stream>>>(h2, exn, batch, n, l1w, l1b, l2w, l2b, (float*)d_out);
}

// Round 10
// 417.500 us; speedup vs baseline: 2.6400x; 2.6400x over previous
//
#include <hip/hip_runtime.h>

typedef float v2f __attribute__((ext_vector_type(2)));

// ---------------- CSR build (split kernels — r8 known-good) ----------------

// zero deg + pack wc1/bc1/wc2/bc2 (all independent) in one launch
__global__ void k_init(const float* __restrict__ w1_l, const float* __restrict__ w1_r,
                       const float* __restrict__ b1_l, const float* __restrict__ b1_r,
                       const float* __restrict__ w2_l, const float* __restrict__ w2_r,
                       const float* __restrict__ b2_l, const float* __restrict__ b2_r,
                       float* __restrict__ wc1, float* __restrict__ bc1,
                       float* __restrict__ wc2, float* __restrict__ bc2,
                       int* __restrict__ deg, int n){
  int i = blockIdx.x*256 + threadIdx.x;
  if (i < n) deg[i] = 0;
  if (i < 128*256){
    int k = i >> 8, j = i & 255;
    wc1[i] = (j < 128) ? w1_l[k*128 + j] : w1_r[k*128 + (j - 128)];
  }
  if (i < 128*128){
    int k = i >> 7, j = i & 127;
    wc2[i] = (j < 64) ? w2_l[k*64 + j] : w2_r[k*64 + (j - 64)];
  }
  if (i < 256) bc1[i] = (i < 128) ? b1_l[i] : b1_r[i - 128];
  if (i < 128) bc2[i] = (i < 64)  ? b2_l[i] : b2_r[i - 64];
}

__global__ void k_hist(const int* __restrict__ dstp, int* __restrict__ deg, int E){
  int e = blockIdx.x*256 + threadIdx.x;
  if (e < E) atomicAdd(&deg[dstp[e]], 1);
}

__global__ void k_scan1(const int* __restrict__ deg, int* __restrict__ rowptr,
                        int* __restrict__ bsum, int n){
  __shared__ int s[256];
  int i = blockIdx.x*256 + threadIdx.x;
  int v = (i < n) ? deg[i] + 1 : 0;   // +1 = self loop
  s[threadIdx.x] = v;
  __syncthreads();
  for (int off = 1; off < 256; off <<= 1){
    int t = (threadIdx.x >= off) ? s[threadIdx.x - off] : 0;
    __syncthreads();
    s[threadIdx.x] += t;
    __syncthreads();
  }
  if (i < n) rowptr[i] = s[threadIdx.x] - v;   // exclusive within block
  if (threadIdx.x == 255) bsum[blockIdx.x] = s[255];
}

__global__ void k_scan2(int* bsum, int nb){
  __shared__ int s[256];
  int v = (threadIdx.x < nb) ? bsum[threadIdx.x] : 0;
  s[threadIdx.x] = v;
  __syncthreads();
  for (int off = 1; off < 256; off <<= 1){
    int t = (threadIdx.x >= off) ? s[threadIdx.x - off] : 0;
    __syncthreads();
    s[threadIdx.x] += t;
    __syncthreads();
  }
  if (threadIdx.x < nb) bsum[threadIdx.x] = s[threadIdx.x] - v;  // exclusive
}

// scan3 + scatter_init fused: finalize rowptr, seed self-loop + cursor
__global__ void k_scan3(int* rowptr, const int* __restrict__ bsum,
                        int* __restrict__ srcs, int* __restrict__ cursor,
                        int n, int total){
  int i = blockIdx.x*256 + threadIdx.x;
  if (i < n){
    int b = rowptr[i] + bsum[blockIdx.x];
    rowptr[i] = b;
    srcs[b] = i;          // self loop at segment head
    cursor[i] = b + 1;
  }
  if (i == 0) rowptr[n] = total;
}

__global__ void k_scatter(const int* __restrict__ srcp, const int* __restrict__ dstp,
                          int* __restrict__ cursor, int* __restrict__ srcs, int E){
  int e = blockIdx.x*256 + threadIdx.x;
  if (e < E){
    int p = atomicAdd(&cursor[dstp[e]], 1);
    srcs[p] = srcp[e];
  }
}

// ---------------- fp32 GEMM 128x128 tile, 8x8 micro (main GEMMs) -----------
// Split-half LDS layout -> 2-way bank alias (free). K%16==0, N%128==0; M guarded.

#define GBM 128
#define GBN 128
#define GBK 16

__device__ __forceinline__ int half_perm(int j){
  return ((j >> 3) << 2) + (j & 3) + ((j & 4) ? 64 : 0);
}

__global__ __launch_bounds__(256, 2) void k_gemm128(
    const float* __restrict__ A, const float* __restrict__ W,
    const float* __restrict__ bias, float* __restrict__ C,
    int M, int K, int N){
  __shared__ float As[GBK][GBM];
  __shared__ float Ws[GBK][GBN];
  int bm = blockIdx.x * GBM, bn = blockIdx.y * GBN;
  int tid = threadIdx.x;
  int tx = tid & 15, ty = tid >> 4;
  float acc[8][8] = {};
  for (int k0 = 0; k0 < K; k0 += GBK){
    #pragma unroll
    for (int l = 0; l < 2; l++){
      int idx = tid + l*256;              // 0..511
      int r = idx >> 2, kq = (idx & 3) * 4;
      float4 v = make_float4(0.f, 0.f, 0.f, 0.f);
      if (bm + r < M) v = *(const float4*)(A + (size_t)(bm + r)*K + k0 + kq);
      int rp = half_perm(r);
      As[kq+0][rp] = v.x; As[kq+1][rp] = v.y; As[kq+2][rp] = v.z; As[kq+3][rp] = v.w;
      int kr = idx >> 5, wc = (idx & 31) * 4;
      int wp = ((wc >> 3) << 2) + ((wc & 4) ? 64 : 0);
      *(float4*)(&Ws[kr][wp]) = *(const float4*)(W + (size_t)(k0 + kr)*N + bn + wc);
    }
    __syncthreads();
    #pragma unroll
    for (int k = 0; k < GBK; k++){
      float a[8], w[8];
      *(float4*)(a)   = *(const float4*)(&As[k][ty*4]);
      *(float4*)(a+4) = *(const float4*)(&As[k][64 + ty*4]);
      *(float4*)(w)   = *(const float4*)(&Ws[k][tx*4]);
      *(float4*)(w+4) = *(const float4*)(&Ws[k][64 + tx*4]);
      #pragma unroll
      for (int i = 0; i < 8; i++)
        #pragma unroll
        for (int j = 0; j < 8; j++)
          acc[i][j] = fmaf(a[i], w[j], acc[i][j]);
    }
    __syncthreads();
  }
  #pragma unroll
  for (int i = 0; i < 8; i++){
    int r = bm + ty*8 + i;
    if (r < M){
      #pragma unroll
      for (int j4 = 0; j4 < 2; j4++){
        float4 o;
        int cb = bn + tx*8 + j4*4;
        o.x = acc[i][j4*4+0] + bias[cb + 0];
        o.y = acc[i][j4*4+1] + bias[cb + 1];
        o.z = acc[i][j4*4+2] + bias[cb + 2];
        o.w = acc[i][j4*4+3] + bias[cb + 3];
        *(float4*)(C + (size_t)r*N + cb) = o;
      }
    }
  }
}

// ---------------- DPP adds (VALU pipe, no DS ops) ----------------

template<int CTRL>
__device__ __forceinline__ float dpp_add(float x){
  int t = __builtin_amdgcn_update_dpp(0, __float_as_int(x), CTRL, 0xf, 0xf, true);
  return x + __int_as_float(t);
}

// 5-step reduce: lane31 = sum(lanes 0..31), lane63 = sum(lanes 32..63)
__device__ __forceinline__ float half_reduce(float x){
  x = dpp_add<0x111>(x);   // row_shr:1
  x = dpp_add<0x112>(x);   // row_shr:2
  x = dpp_add<0x114>(x);   // row_shr:4
  x = dpp_add<0x118>(x);   // row_shr:8
  x = dpp_add<0x142>(x);   // row_bcast:15
  return x;
}

// ---------------- fused GATv2 layer: 2 edges/iter, packed fp32 ------------
// One wave per (node, head). Lanes 0-31 = edge A, 32-63 = edge B; each lane
// holds a float2 feature pair -> v_pk_* ops. 4 pairs (8 edges) unrolled for
// memory-level parallelism. Score: 5-step DPP half-wave reduce (both edges
// simultaneously). 32-bit base+offset addressing (saddr form).
// xlr layout: [n][H*128]: xl head-major at [h*64..), xr at [H*64 + h*64..).

template<int H>
__global__ __launch_bounds__(256) void k_gat_fused(
    const float* __restrict__ xlr, const int* __restrict__ rowptr,
    const int* __restrict__ srcs, const float* __restrict__ att,
    const float* __restrict__ bias, float* __restrict__ out, int n){
  int gid = blockIdx.x * blockDim.x + threadIdx.x;
  int wave = gid >> 6, lane = gid & 63;
  int nd = wave / H, h = wave % H;
  if (nd >= n) return;
  constexpr int SHIFTB = (H == 2) ? 10 : 9;     // bytes per node row
  const bool hi = lane >= 32;
  const int fpos = h*64 + ((lane & 31) << 1);   // float-pair offset in row
  const unsigned foff = (unsigned)fpos * 4u;    // byte offset within row
  const char* __restrict__ xbase = (const char*)xlr;
  v2f xr = *(const v2f*)(xlr + (size_t)nd*(H*128) + H*64 + fpos);
  v2f av = *(const v2f*)(att + fpos);
  const v2f c02 = {0.2f, 0.2f};
  v2f acc = {0.f, 0.f};
  float den = 0.f;
  int s0 = rowptr[nd], s1 = rowptr[nd+1];
  for (int base = s0; base < s1; base += 64){
    int idx = base + lane;
    int sv = (idx < s1) ? srcs[idx] : 0;   // pad lanes hold 0 (valid row)
    int cnt = min(64, s1 - base);
    auto pair = [&](int i, bool dual){
      int a0 = __builtin_amdgcn_readlane(sv, i);
      int a1 = dual ? __builtin_amdgcn_readlane(sv, i+1) : a0;
      int a  = hi ? a1 : a0;
      v2f xv = *(const v2f*)(xbase + (((unsigned)a << SHIFTB) + foff));
      v2f t  = xv + xr;
      v2f lt = __builtin_elementwise_max(t, t * c02);   // leaky_relu 0.2
      v2f pr = lt * av;
      float p = pr.x + pr.y;
      p = half_reduce(p);                  // lane31 = scA, lane63 = scB
      float sA = __int_as_float(__builtin_amdgcn_readlane(__float_as_int(p), 31));
      float sB = __int_as_float(__builtin_amdgcn_readlane(__float_as_int(p), 63));
      float ex = __expf(hi ? sB : sA);     // scores bounded; softmax w/o max
      if (!dual) ex = hi ? 0.f : ex;       // odd tail: half B contributes 0
      den += ex;
      v2f exv = {ex, ex};
      acc += xv * exv;
    };
    int i = 0;
    for (; i + 8 <= cnt; i += 8){
      pair(i+0, true); pair(i+2, true); pair(i+4, true); pair(i+6, true);
    }
    for (; i < cnt; i += 2) pair(i, i + 1 < cnt);
  }
  // combine the two halves (once per node)
  float denT = den + __shfl_xor(den, 32, 64);
  float ax = acc.x + __shfl_xor(acc.x, 32, 64);
  float ay = acc.y + __shfl_xor(acc.y, 32, 64);
  if (!hi){
    v2f bv = *(const v2f*)(bias + fpos);
    float inv = 1.f / (denT + 1e-16f);
    v2f o = {ax*inv + bv.x, ay*inv + bv.y};
    v2f z = {0.f, 0.f};
    o = __builtin_elementwise_max(o, z);
    *(v2f*)(out + (size_t)nd*(H*64) + fpos) = o;
  }
}

// ---------------- gate: relu(h2@gw1+gb1)@gw2+gb2 -> exp, fused ------------

__global__ __launch_bounds__(256) void k_gate(
    const float* __restrict__ h2, const float* __restrict__ gw1,
    const float* __restrict__ gb1, const float* __restrict__ gw2,
    const float* __restrict__ gb2, float* __restrict__ exn, int M){
  __shared__ float As[32][64 + 4];
  __shared__ float Ws[32][64];
  int bm = blockIdx.x * 64;
  int tid = threadIdx.x;
  int tx = tid & 15, ty = tid >> 4;
  float acc[4][4] = {};
  for (int k0 = 0; k0 < 64; k0 += 32){
    #pragma unroll
    for (int l = 0; l < 2; l++){
      int idx = tid + l*256;
      int r = idx >> 3, c4 = (idx & 7) * 4;
      float4 v = make_float4(0.f, 0.f, 0.f, 0.f);
      if (bm + r < M) v = *(const float4*)(h2 + (size_t)(bm + r)*64 + k0 + c4);
      As[c4+0][r] = v.x; As[c4+1][r] = v.y; As[c4+2][r] = v.z; As[c4+3][r] = v.w;
      int kr = idx >> 4, wc4 = (idx & 15) * 4;
      *(float4*)(&Ws[kr][wc4]) = *(const float4*)(gw1 + (size_t)(k0 + kr)*64 + wc4);
    }
    __syncthreads();
    #pragma unroll
    for (int k = 0; k < 32; k++){
      float4 a4 = *(const float4*)(&As[k][ty*4]);
      float4 w4 = *(const float4*)(&Ws[k][tx*4]);
      float av[4] = {a4.x, a4.y, a4.z, a4.w};
      float wv[4] = {w4.x, w4.y, w4.z, w4.w};
      #pragma unroll
      for (int i = 0; i < 4; i++)
        #pragma unroll
        for (int j = 0; j < 4; j++)
          acc[i][j] = fmaf(av[i], wv[j], acc[i][j]);
    }
    __syncthreads();
  }
  float4 b4 = *(const float4*)(gb1 + tx*4);
  float4 w2 = *(const float4*)(gw2 + tx*4);
  float gb2v = gb2[0];
  #pragma unroll
  for (int i = 0; i < 4; i++){
    float p = fmaxf(acc[i][0] + b4.x, 0.f) * w2.x;
    p = fmaf(fmaxf(acc[i][1] + b4.y, 0.f), w2.y, p);
    p = fmaf(fmaxf(acc[i][2] + b4.z, 0.f), w2.z, p);
    p = fmaf(fmaxf(acc[i][3] + b4.w, 0.f), w2.w, p);
    p = dpp_add<0x111>(p);
    p = dpp_add<0x112>(p);
    p = dpp_add<0x114>(p);
    p = dpp_add<0x118>(p);     // lane tx==15 holds the 16-lane row sum
    if (tx == 15){
      int r = bm + ty*4 + i;
      if (r < M) exn[r] = __expf(p + gb2v);
    }
  }
}

// ---------------- pool + MLP head: one block per batch segment ----------------

__global__ __launch_bounds__(1024) void k_pool_mlp(
    const float* __restrict__ h2, const float* __restrict__ exn,
    const int* __restrict__ batch, int n,
    const float* __restrict__ l1w, const float* __restrict__ l1b,
    const float* __restrict__ l2w, const float* __restrict__ l2b,
    float* __restrict__ out){
  __shared__ float accs[16][64];
  __shared__ float dens[16];
  int b = blockIdx.x;
  int tid = threadIdx.x, lane = tid & 63, wv = tid >> 6;
  int lo = 0, hi = n;
  while (lo < hi){ int m = (lo + hi) >> 1; if (batch[m] < b) lo = m + 1; else hi = m; }
  int start = lo;
  hi = n;
  while (lo < hi){ int m = (lo + hi) >> 1; if (batch[m] < b + 1) lo = m + 1; else hi = m; }
  int end = lo;
  float acc = 0.f, den = 0.f;
  for (int nd = start + wv; nd < end; nd += 16){
    float ex = exn[nd];
    den += ex;
    acc = fmaf(ex, h2[(size_t)nd*64 + lane], acc);
  }
  accs[wv][lane] = acc;
  if (lane == 0) dens[wv] = den;
  __syncthreads();
  if (wv == 0){
    float p = 0.f, d = 0.f;
    #pragma unroll
    for (int w = 0; w < 16; w++){ p += accs[w][lane]; d += dens[w]; }
    p = p / (d + 1e-16f);
    float t = l1b[lane];
    #pragma unroll
    for (int k = 0; k < 64; k++)
      t = fmaf(__shfl(p, k, 64), l1w[k*64 + lane], t);
    t = fmaxf(t, 0.f) * l2w[lane];
    #pragma unroll
    for (int off = 32; off; off >>= 1) t += __shfl_xor(t, off, 64);
    if (lane == 0) out[b] = t + l2b[0];
  }
}

// ---------------- launch (12 dispatches) ----------------

extern "C" void kernel_launch(void* const* d_in, const int* in_sizes, int n_in,
                              void* d_out, int out_size, void* d_ws, size_t ws_size,
                              hipStream_t stream){
  const float* x    = (const float*)d_in[0];
  const int*   ei   = (const int*)  d_in[1];
  const int*   batch= (const int*)  d_in[2];
  const float* w1_l = (const float*)d_in[3];  const float* b1_l = (const float*)d_in[4];
  const float* w1_r = (const float*)d_in[5];  const float* b1_r = (const float*)d_in[6];
  const float* att1 = (const float*)d_in[7];  const float* bias1= (const float*)d_in[8];
  const float* w2_l = (const float*)d_in[9];  const float* b2_l = (const float*)d_in[10];
  const float* w2_r = (const float*)d_in[11]; const float* b2_r = (const float*)d_in[12];
  const float* att2 = (const float*)d_in[13]; const float* bias2= (const float*)d_in[14];
  const float* gw1  = (const float*)d_in[15]; const float* gb1  = (const float*)d_in[16];
  const float* gw2  = (const float*)d_in[17]; const float* gb2  = (const float*)d_in[18];
  const float* l1w  = (const float*)d_in[19]; const float* l1b  = (const float*)d_in[20];
  const float* l2w  = (const float*)d_in[21]; const float* l2b  = (const float*)d_in[22];

  const int n = in_sizes[0] / 128;
  const int E = in_sizes[1] / 2;
  const int Bb = out_size;
  const int Etot = E + n;
  const int* srcp = ei;
  const int* dstp = ei + E;

  char* wsbase = (char*)d_ws;
  size_t off = 0;
  auto alloc = [&](size_t bytes)->char*{
    char* p = wsbase + off;
    off = (off + bytes + 255) & ~(size_t)255;
    return p;
  };
  int*   deg    = (int*)  alloc((size_t)n*4);
  int*   rowptr = (int*)  alloc((size_t)(n+1)*4);
  int*   cursor = (int*)  alloc((size_t)n*4);
  int*   bsum   = (int*)  alloc(1024);
  int*   srcs   = (int*)  alloc((size_t)Etot*4);
  float* wc1    = (float*)alloc(128*256*4);
  float* bc1    = (float*)alloc(256*4);
  float* wc2    = (float*)alloc(128*128*4);
  float* bc2    = (float*)alloc(128*4);
  float* big    = (float*)alloc((size_t)n*256*4);  // xlr1; later xlr2 + h2
  float* h1     = (float*)alloc((size_t)n*128*4);  // h1; later exn
  float* xlr1 = big;
  float* xlr2 = big;
  float* h2   = big + (size_t)n*128;
  float* exn  = h1;                     // reuse after layer-2 gemm consumed h1

  int nb = (n + 255) / 256;
  int eb = (E + 255) / 256;
  int ib = (((n > 32768) ? n : 32768) + 255) / 256;

  // CSR build + weight packing
  k_init<<<ib, 256, 0, stream>>>(w1_l, w1_r, b1_l, b1_r, w2_l, w2_r, b2_l, b2_r,
                                 wc1, bc1, wc2, bc2, deg, n);
  k_hist<<<eb, 256, 0, stream>>>(dstp, deg, E);
  k_scan1<<<nb, 256, 0, stream>>>(deg, rowptr, bsum, n);
  k_scan2<<<1, 256, 0, stream>>>(bsum, nb);
  k_scan3<<<nb, 256, 0, stream>>>(rowptr, bsum, srcs, cursor, n, Etot);
  k_scatter<<<eb, 256, 0, stream>>>(srcp, dstp, cursor, srcs, E);

  // layer 1
  dim3 g1((n + GBM - 1)/GBM, 256/GBN);
  k_gemm128<<<g1, 256, 0, stream>>>(x, wc1, bc1, xlr1, n, 128, 256);
  long long thr1 = (long long)n * 2 * 64;
  k_gat_fused<2><<<(int)((thr1 + 255)/256), 256, 0, stream>>>(xlr1, rowptr, srcs, att1, bias1, h1, n);

  // layer 2
  dim3 g2((n + GBM - 1)/GBM, 128/GBN);
  k_gemm128<<<g2, 256, 0, stream>>>(h1, wc2, bc2, xlr2, n, 128, 128);
  long long thr2 = (long long)n * 64;
  k_gat_fused<1><<<(int)((thr2 + 255)/256), 256, 0, stream>>>(xlr2, rowptr, srcs, att2, bias2, h2, n);

  // gate (gemm + gw2-dot + exp fused)
  k_gate<<<(n + 63)/64, 256, 0, stream>>>(h2, gw1, gb1, gw2, gb2, exn, n);

  // pool + MLP head
  k_pool_mlp<<<Bb, 1024, 0, stream>>>(h2, exn, batch, n, l1w, l1b, l2w, l2b, (float*)d_out);
}